// Round 19
// baseline (83.793 us; speedup 1.0000x reference)
//
#include <hip/hip_runtime.h>
#include <hip/hip_bf16.h>

#define BB 8
#define TT_DIM 128
#define SS 512
#define DD 512
#define TANH_SCALE 2.885390081777927f   // 2*log2(e)
#define LOG2E 1.4426950408889634f

typedef unsigned short u16;
typedef unsigned int u32;
typedef short short8 __attribute__((ext_vector_type(8)));
typedef short short4v __attribute__((ext_vector_type(4)));
typedef float f32x2 __attribute__((ext_vector_type(2)));
typedef float f32x4 __attribute__((ext_vector_type(4)));
typedef unsigned int u32x4 __attribute__((ext_vector_type(4)));

__device__ __forceinline__ u16 f2bf(float f) {
  __hip_bfloat16 h = __float2bfloat16(f);
  return __builtin_bit_cast(u16, h);
}
__device__ __forceinline__ float bfhi2f(u32 w) {
  return __builtin_bit_cast(float, w & 0xFFFF0000u);
}
__device__ __forceinline__ float bflo2f(u32 w) {
  return __builtin_bit_cast(float, w << 16);
}
__device__ __forceinline__ f32x2 vlo(f32x4 v) {
  return __builtin_shufflevector(v, v, 0, 1);
}
__device__ __forceinline__ f32x2 vhi(f32x4 v) {
  return __builtin_shufflevector(v, v, 2, 3);
}
__device__ __forceinline__ f32x2 splat2(float x) {
  f32x2 v; v.x = x; v.y = x; return v;
}
__device__ __forceinline__ short8 cvt8(f32x4 a, f32x4 b) {
  short8 o;
  o[0] = (short)f2bf(a[0]); o[1] = (short)f2bf(a[1]);
  o[2] = (short)f2bf(a[2]); o[3] = (short)f2bf(a[3]);
  o[4] = (short)f2bf(b[0]); o[5] = (short)f2bf(b[1]);
  o[6] = (short)f2bf(b[2]); o[7] = (short)f2bf(b[3]);
  return o;
}

// ---------------------------------------------------------------------------
// Fused dual-GEMM (unchanged from R17).
// bx<16:   A=output:  E2=exp(2*(A@dec_w+dec_b)) interleaved [t>>1][d][t&1],
//                     G=A@out_w2+out_b
// bx>=16:  A=context: Ftp=exp(2*(A@attn_w+attn_b)) packed^T bf16,
//                     Ht=(A@out_w1)^T bf16
// ---------------------------------------------------------------------------
__global__ __launch_bounds__(256) void ef_gemm(
    const float* __restrict__ output, const float* __restrict__ context,
    const float* __restrict__ dec_w, const float* __restrict__ attn_w,
    const float* __restrict__ out_w,
    const float* __restrict__ dec_b, const float* __restrict__ attn_b,
    const float* __restrict__ out_b,
    float* __restrict__ E2, u16* __restrict__ Ftp,
    float* __restrict__ G, u16* __restrict__ Ht) {
  int bx = blockIdx.x;
  bool isF = bx >= 16;
  const float* A  = isF ? context : output;
  const float* B1 = isF ? attn_w : dec_w;
  const float* B2 = isF ? out_w : out_w + 512 * 512;
  const float* bias1 = isF ? attn_b : dec_b;
  int m0 = (isF ? bx - 16 : bx) * 64;
  int n0 = blockIdx.y * 64;

  __shared__ u16 As[64][40];
  __shared__ u16 Bs1[64][40];
  __shared__ u16 Bs2[64][40];
  int t = threadIdx.x;
  int lane = t & 63, wid = t >> 6, wm = wid >> 1, wn = wid & 1;
  int ar = t >> 2, ac = (t & 3) * 8;
  int bn = t & 63, bk0 = (t >> 6) * 8;
  int fr = lane & 15, fh = (lane >> 4) * 8;

  const f32x4 fzero = {0.f, 0.f, 0.f, 0.f};
  f32x4 acc1[2][2], acc2[2][2];
#pragma unroll
  for (int i = 0; i < 2; ++i)
#pragma unroll
    for (int j = 0; j < 2; ++j) { acc1[i][j] = fzero; acc2[i][j] = fzero; }

  short8 av, bv1, bv2;
  auto loadA = [&](int k0) {
    const float* p = A + (size_t)(m0 + ar) * 512 + k0 + ac;
    av = cvt8(*(const f32x4*)p, *(const f32x4*)(p + 4));
  };
  auto loadB = [&](const float* B, int k0, short8& dst) {
    const float* p = B + (size_t)(k0 + bk0) * 512 + n0 + bn;
#pragma unroll
    for (int i = 0; i < 8; ++i) dst[i] = (short)f2bf(p[(size_t)i * 512]);
  };

  loadA(0); loadB(B1, 0, bv1); loadB(B2, 0, bv2);
  for (int k0 = 0; k0 < 512; k0 += 32) {
    if (k0) __syncthreads();
    *(short8*)&As[ar][ac] = av;
    *(short8*)&Bs1[bn][bk0] = bv1;
    *(short8*)&Bs2[bn][bk0] = bv2;
    __syncthreads();
    short8 a0 = *(const short8*)&As[wm * 32 + fr][fh];
    short8 a1 = *(const short8*)&As[wm * 32 + 16 + fr][fh];
    short8 p0 = *(const short8*)&Bs1[wn * 32 + fr][fh];
    short8 p1 = *(const short8*)&Bs1[wn * 32 + 16 + fr][fh];
    short8 r0 = *(const short8*)&Bs2[wn * 32 + fr][fh];
    short8 r1 = *(const short8*)&Bs2[wn * 32 + 16 + fr][fh];
    if (k0 + 32 < 512) { loadA(k0 + 32); loadB(B1, k0 + 32, bv1); loadB(B2, k0 + 32, bv2); }
    acc1[0][0] = __builtin_amdgcn_mfma_f32_16x16x32_bf16(a0, p0, acc1[0][0], 0, 0, 0);
    acc1[0][1] = __builtin_amdgcn_mfma_f32_16x16x32_bf16(a0, p1, acc1[0][1], 0, 0, 0);
    acc1[1][0] = __builtin_amdgcn_mfma_f32_16x16x32_bf16(a1, p0, acc1[1][0], 0, 0, 0);
    acc1[1][1] = __builtin_amdgcn_mfma_f32_16x16x32_bf16(a1, p1, acc1[1][1], 0, 0, 0);
    acc2[0][0] = __builtin_amdgcn_mfma_f32_16x16x32_bf16(a0, r0, acc2[0][0], 0, 0, 0);
    acc2[0][1] = __builtin_amdgcn_mfma_f32_16x16x32_bf16(a0, r1, acc2[0][1], 0, 0, 0);
    acc2[1][0] = __builtin_amdgcn_mfma_f32_16x16x32_bf16(a1, r0, acc2[1][0], 0, 0, 0);
    acc2[1][1] = __builtin_amdgcn_mfma_f32_16x16x32_bf16(a1, r1, acc2[1][1], 0, 0, 0);
  }

  // C/D layout (m89): col = lane&15, row = (lane>>4)*4 + j
#pragma unroll
  for (int qa = 0; qa < 2; ++qa) {
    int rbase = wm * 32 + qa * 16 + ((lane >> 4) << 2);
#pragma unroll
    for (int qn = 0; qn < 2; ++qn) {
      int col = n0 + wn * 32 + qn * 16 + (lane & 15);
      float b1v = bias1[col];
      int bb = m0 >> 9;
      int srow = (m0 & 511) + rbase;
      if (isF) {
        size_t fbase = ((size_t)bb * 64 + (col >> 3)) * 4096 + (size_t)(col & 7);
        short4v ho;
#pragma unroll
        for (int j = 0; j < 4; ++j) {
          float v1 = __builtin_amdgcn_exp2f((acc1[qa][qn][j] + b1v) * TANH_SCALE);
          Ftp[fbase + (size_t)(srow + j) * 8] = f2bf(v1);
          ho[j] = (short)f2bf(acc2[qa][qn][j]);
        }
        *(short4v*)&Ht[((size_t)bb * 512 + col) * 512 + srow] = ho;
      } else {
        float b2v = out_b[col];
#pragma unroll
        for (int j = 0; j < 4; ++j) {
          float v1 = __builtin_amdgcn_exp2f((acc1[qa][qn][j] + b1v) * TANH_SCALE);
          int row = m0 + rbase + j;
          E2[(((size_t)row >> 1) * 512 + col) * 2 + (row & 1)] = v1;
          G[(size_t)row * 512 + col] = acc2[qa][qn][j] + b2v;
        }
      }
    }
  }
}

// ---------------------------------------------------------------------------
// final: out = tanh(attn_bf @ Ht^T + G). 32x64 tile, grid (32,8). (R17)
// ---------------------------------------------------------------------------
__global__ __launch_bounds__(256) void final_gemm(
    const u16* __restrict__ attn_bf, const u16* __restrict__ Ht,
    const float* __restrict__ G, float* __restrict__ out) {
  int m0 = blockIdx.x * 32, n0 = blockIdx.y * 64;
  int b = m0 >> 7;   // T = 128
  const u16* Htb = Ht + (size_t)b * 512 * 512;

  __shared__ u16 As[32][40];
  __shared__ u16 Bs[64][40];
  int t = threadIdx.x;
  int lane = t & 63, wid = t >> 6, wm = wid >> 1, wn = wid & 1;
  int ar = t >> 2, ac = (t & 3) * 8;
  int bn = t & 63, bk0 = (t >> 6) * 8;
  int fr = lane & 15, fh = (lane >> 4) * 8;

  const f32x4 fzero = {0.f, 0.f, 0.f, 0.f};
  f32x4 acc[2] = {fzero, fzero};

  short8 av, bv;
  auto loadA = [&](int k0) {
    if (t < 128)
      av = *(const short8*)(attn_bf + (size_t)(m0 + ar) * 512 + k0 + ac);
  };
  auto loadB = [&](int k0) {
    bv = *(const short8*)(Htb + (size_t)(n0 + bn) * 512 + k0 + bk0);
  };

  loadA(0); loadB(0);
  for (int k0 = 0; k0 < 512; k0 += 32) {
    if (k0) __syncthreads();
    if (t < 128) *(short8*)&As[ar][ac] = av;
    *(short8*)&Bs[bn][bk0] = bv;
    __syncthreads();
    short8 a0 = *(const short8*)&As[wm * 16 + fr][fh];
    short8 b0 = *(const short8*)&Bs[wn * 32 + fr][fh];
    short8 b1 = *(const short8*)&Bs[wn * 32 + 16 + fr][fh];
    if (k0 + 32 < 512) { loadA(k0 + 32); loadB(k0 + 32); }
    acc[0] = __builtin_amdgcn_mfma_f32_16x16x32_bf16(a0, b0, acc[0], 0, 0, 0);
    acc[1] = __builtin_amdgcn_mfma_f32_16x16x32_bf16(a0, b1, acc[1], 0, 0, 0);
  }

  int row0 = m0 + wm * 16 + ((lane >> 4) << 2);
#pragma unroll
  for (int qn = 0; qn < 2; ++qn) {
    int col = n0 + wn * 32 + qn * 16 + (lane & 15);
#pragma unroll
    for (int j = 0; j < 4; ++j) {
      float v = acc[qn][j] + G[(size_t)(row0 + j) * 512 + col];
      float e = __builtin_amdgcn_exp2f(v * TANH_SCALE);
      v = fmaf(-2.0f, __builtin_amdgcn_rcpf(e + 1.0f), 1.0f);
      out[(size_t)(row0 + j) * 512 + col] = v;
    }
  }
}

// ---------------------------------------------------------------------------
// Fused logits+softmax (R17) + EXPLICIT 2-deep load pipeline.
// grid = B*T/4 = 256 (XCD-swizzled), block = 1024 (16 waves).
// Wave (gh, sc): rows bt0..bt0+3 as 2 pairs, g in [gh*32,+32), s-chunk sc.
// Two named load sets (A/B) ping-pong: next-g {F dwordx4, 8x E2 f32x4,
// 2x q f32x4} issue while current g computes -> latency hidden (R18 PMC:
// VALUBusy 42%, VGPR 32 = compiler wasn't pipelining).
// ---------------------------------------------------------------------------
__global__ __launch_bounds__(1024) void logits_softmax_kernel(
    const float* __restrict__ E2, const u16* __restrict__ Ftp,
    const float* __restrict__ qw,
    float* __restrict__ attn, u16* __restrict__ attn_bf) {
  int bid = blockIdx.x;
  int logical = ((bid & 7) << 5) | (bid >> 3);  // batch = bid&7 per XCD
  int bt0 = logical * 4;
  int b = logical >> 5;
  int tid = threadIdx.x;
  int lane = tid & 63;
  int wv = __builtin_amdgcn_readfirstlane(tid >> 6);
  int gh = wv >> 3;
  int sc = wv & 7;
  int s = sc * 64 + lane;

  const u32x4* Fp = (const u32x4*)(Ftp + (size_t)b * 262144 + (size_t)s * 8);
  const float* E2p0 = E2 + ((size_t)(bt0 >> 1)) * 1024;
  const float* E2p1 = E2p0 + 1024;

  const f32x2 one2 = {1.f, 1.f};
  f32x2 aP0A = {0.f, 0.f}, aP0B = {0.f, 0.f};
  f32x2 aP1A = {0.f, 0.f}, aP1B = {0.f, 0.f};

  auto quadpk = [&](f32x2 e0, f32x2 e1, f32x2 e2, f32x2 e3,
                    f32x2 ff0, f32x2 ff1, f32x2 ff2, f32x2 ff3,
                    float q0, float q1, float q2, float q3, f32x2& acc) {
    f32x2 x0 = e0 * ff0 + one2, x1 = e1 * ff1 + one2;
    f32x2 x2 = e2 * ff2 + one2, x3 = e3 * ff3 + one2;
    f32x2 dA = x0 * x1, dB = x2 * x3;
    f32x2 nA = q0 * x1 + q1 * x0;
    f32x2 nB = q2 * x3 + q3 * x2;
    f32x2 N = nA * dB + nB * dA;
    f32x2 D = dA * dB;
    f32x2 r;
    r.x = __builtin_amdgcn_rcpf(D.x);
    r.y = __builtin_amdgcn_rcpf(D.y);
    acc += N * r;
  };

  // ---- explicit 2-deep pipeline: named set A / set B ----
  u32x4 wA, wB;
  f32x4 qA0, qA1, qB0, qB1;
  f32x4 eA0, eA1, eA2, eA3, eA4, eA5, eA6, eA7;
  f32x4 eB0, eB1, eB2, eB3, eB4, eB5, eB6, eB7;

  auto loadSetA = [&](int g) {
    wA = Fp[(size_t)g * 512];
    qA0 = *(const f32x4*)(qw + g * 8);
    qA1 = *(const f32x4*)(qw + g * 8 + 4);
    eA0 = *(const f32x4*)(E2p0 + g * 16);
    eA1 = *(const f32x4*)(E2p0 + g * 16 + 4);
    eA2 = *(const f32x4*)(E2p0 + g * 16 + 8);
    eA3 = *(const f32x4*)(E2p0 + g * 16 + 12);
    eA4 = *(const f32x4*)(E2p1 + g * 16);
    eA5 = *(const f32x4*)(E2p1 + g * 16 + 4);
    eA6 = *(const f32x4*)(E2p1 + g * 16 + 8);
    eA7 = *(const f32x4*)(E2p1 + g * 16 + 12);
  };
  auto loadSetB = [&](int g) {
    wB = Fp[(size_t)g * 512];
    qB0 = *(const f32x4*)(qw + g * 8);
    qB1 = *(const f32x4*)(qw + g * 8 + 4);
    eB0 = *(const f32x4*)(E2p0 + g * 16);
    eB1 = *(const f32x4*)(E2p0 + g * 16 + 4);
    eB2 = *(const f32x4*)(E2p0 + g * 16 + 8);
    eB3 = *(const f32x4*)(E2p0 + g * 16 + 12);
    eB4 = *(const f32x4*)(E2p1 + g * 16);
    eB5 = *(const f32x4*)(E2p1 + g * 16 + 4);
    eB6 = *(const f32x4*)(E2p1 + g * 16 + 8);
    eB7 = *(const f32x4*)(E2p1 + g * 16 + 12);
  };
  auto computeSet = [&](u32x4 w, f32x4 q0v, f32x4 q1v,
                        f32x4 ea0, f32x4 eb0, f32x4 ec0, f32x4 ed0,
                        f32x4 ea1, f32x4 eb1, f32x4 ec1, f32x4 ed1) {
    f32x2 ff0 = splat2(bflo2f(w[0])), ff1 = splat2(bfhi2f(w[0]));
    f32x2 ff2 = splat2(bflo2f(w[1])), ff3 = splat2(bfhi2f(w[1]));
    f32x2 ff4 = splat2(bflo2f(w[2])), ff5 = splat2(bfhi2f(w[2]));
    f32x2 ff6 = splat2(bflo2f(w[3])), ff7 = splat2(bfhi2f(w[3]));
    quadpk(vlo(ea0), vhi(ea0), vlo(eb0), vhi(eb0),
           ff0, ff1, ff2, ff3, q0v[0], q0v[1], q0v[2], q0v[3], aP0A);
    quadpk(vlo(ec0), vhi(ec0), vlo(ed0), vhi(ed0),
           ff4, ff5, ff6, ff7, q1v[0], q1v[1], q1v[2], q1v[3], aP0B);
    quadpk(vlo(ea1), vhi(ea1), vlo(eb1), vhi(eb1),
           ff0, ff1, ff2, ff3, q0v[0], q0v[1], q0v[2], q0v[3], aP1A);
    quadpk(vlo(ec1), vhi(ec1), vlo(ed1), vhi(ed1),
           ff4, ff5, ff6, ff7, q1v[0], q1v[1], q1v[2], q1v[3], aP1B);
  };

  int gbase = gh * 32;
  loadSetA(gbase);
#pragma unroll 4
  for (int gg = 0; gg < 32; gg += 2) {
    loadSetB(gbase + gg + 1);
    computeSet(wA, qA0, qA1, eA0, eA1, eA2, eA3, eA4, eA5, eA6, eA7);
    if (gg + 2 < 32) loadSetA(gbase + gg + 2);
    computeSet(wB, qB0, qB1, eB0, eB1, eB2, eB3, eB4, eB5, eB6, eB7);
  }

  __shared__ float part[2][4][512];   // [gh][row][s]  16 KB
  part[gh][0][s] = aP0A.x + aP0B.x;
  part[gh][1][s] = aP0A.y + aP0B.y;
  part[gh][2][s] = aP1A.x + aP1B.x;
  part[gh][3][s] = aP1A.y + aP1B.y;
  __syncthreads();

  // combine + softmax: row r = tid>>8 (0..3), cols ss and ss+256.
  int r = tid >> 8;
  int ss = tid & 255;
  int wir = (tid >> 6) & 3;
  float l0 = -2.f * (part[0][r][ss] + part[1][r][ss]);
  float l1 = -2.f * (part[0][r][ss + 256] + part[1][r][ss + 256]);

  __shared__ float rmax[4][4], rsum[4][4];
  float m = fmaxf(l0, l1);
#pragma unroll
  for (int off = 32; off > 0; off >>= 1) m = fmaxf(m, __shfl_xor(m, off, 64));
  if (lane == 0) rmax[r][wir] = m;
  __syncthreads();
  float M = fmaxf(fmaxf(rmax[r][0], rmax[r][1]), fmaxf(rmax[r][2], rmax[r][3]));
  float ex0 = __builtin_amdgcn_exp2f((l0 - M) * LOG2E);
  float ex1 = __builtin_amdgcn_exp2f((l1 - M) * LOG2E);
  float sv = ex0 + ex1;
#pragma unroll
  for (int off = 32; off > 0; off >>= 1) sv += __shfl_xor(sv, off, 64);
  if (lane == 0) rsum[r][wir] = sv;
  __syncthreads();
  float S = (rsum[r][0] + rsum[r][1]) + (rsum[r][2] + rsum[r][3]);
  float inv = __builtin_amdgcn_rcpf(S);
  float o0 = ex0 * inv, o1 = ex1 * inv;
  size_t i0 = (size_t)(bt0 + r) * 512 + ss;
  attn[i0] = o0;
  attn[i0 + 256] = o1;
  attn_bf[i0] = f2bf(o0);
  attn_bf[i0 + 256] = f2bf(o1);
}

extern "C" void kernel_launch(void* const* d_in, const int* in_sizes, int n_in,
                              void* d_out, int out_size, void* d_ws, size_t ws_size,
                              hipStream_t stream) {
  const float* output  = (const float*)d_in[0];  // [B,T,D]
  const float* context = (const float*)d_in[1];  // [B,S,C]
  const float* dec_w   = (const float*)d_in[2];  // [D,D]
  const float* dec_b   = (const float*)d_in[3];
  const float* attn_w  = (const float*)d_in[4];  // [C,D]
  const float* attn_b  = (const float*)d_in[5];
  const float* qw      = (const float*)d_in[6];  // [D,1]
  const float* qb      = (const float*)d_in[7];  // [1]  (unused: softmax-invariant)
  const float* out_w   = (const float*)d_in[8];  // [1024,512]
  const float* out_b   = (const float*)d_in[9];
  (void)qb;

  float* out_p  = (float*)d_out;                     // [B,T,D]
  float* attn_p = out_p + (size_t)BB * TT_DIM * DD;  // [B,T,S]

  char* p = (char*)d_ws;
  float* E2   = (float*)p; p += (size_t)BB * TT_DIM * DD * 4;  // 2MB interleaved
  u16* Ftp    = (u16*)p;   p += (size_t)BB * SS * DD * 2;      // 4MB packed^T bf16
  float* G    = (float*)p; p += (size_t)BB * TT_DIM * DD * 4;  // 2MB
  u16* Ht     = (u16*)p;   p += (size_t)BB * SS * DD * 2;      // 4MB bf16 ^T
  u16* attnbf = (u16*)p;   p += (size_t)BB * TT_DIM * SS * 2;  // 1MB

  ef_gemm<<<dim3(80, 8), 256, 0, stream>>>(output, context, dec_w, attn_w,
                                           out_w, dec_b, attn_b, out_b,
                                           E2, Ftp, G, Ht);
  logits_softmax_kernel<<<dim3(BB * TT_DIM / 4), 1024, 0, stream>>>(
      E2, Ftp, qw, attn_p, attnbf);
  final_gemm<<<dim3(32, 8), 256, 0, stream>>>(attnbf, Ht, G, out_p);
}

// Round 20
// 58.779 us; speedup vs baseline: 1.4256x; 1.4256x over previous
//
#include <hip/hip_runtime.h>
#include <hip/hip_bf16.h>

#define BB 8
#define TT_DIM 128
#define SS 512
#define DD 512
#define TANH_SCALE 2.885390081777927f   // 2*log2(e)
#define LOG2E 1.4426950408889634f

typedef unsigned short u16;
typedef unsigned int u32;
typedef short short8 __attribute__((ext_vector_type(8)));
typedef short short4v __attribute__((ext_vector_type(4)));
typedef float f32x2 __attribute__((ext_vector_type(2)));
typedef float f32x4 __attribute__((ext_vector_type(4)));
typedef unsigned int u32x4 __attribute__((ext_vector_type(4)));

__device__ __forceinline__ u16 f2bf(float f) {
  __hip_bfloat16 h = __float2bfloat16(f);
  return __builtin_bit_cast(u16, h);
}
__device__ __forceinline__ float bfhi2f(u32 w) {
  return __builtin_bit_cast(float, w & 0xFFFF0000u);
}
__device__ __forceinline__ float bflo2f(u32 w) {
  return __builtin_bit_cast(float, w << 16);
}
__device__ __forceinline__ f32x2 vlo(f32x4 v) {
  return __builtin_shufflevector(v, v, 0, 1);
}
__device__ __forceinline__ f32x2 vhi(f32x4 v) {
  return __builtin_shufflevector(v, v, 2, 3);
}
__device__ __forceinline__ f32x2 splat2(float x) {
  f32x2 v; v.x = x; v.y = x; return v;
}
__device__ __forceinline__ short8 cvt8(f32x4 a, f32x4 b) {
  short8 o;
  o[0] = (short)f2bf(a[0]); o[1] = (short)f2bf(a[1]);
  o[2] = (short)f2bf(a[2]); o[3] = (short)f2bf(a[3]);
  o[4] = (short)f2bf(b[0]); o[5] = (short)f2bf(b[1]);
  o[6] = (short)f2bf(b[2]); o[7] = (short)f2bf(b[3]);
  return o;
}

// ---------------------------------------------------------------------------
// Fused dual-GEMM.
// bx<16:   A=output:  E2=exp(2*(A@dec_w+dec_b)) interleaved [t>>1][d][t&1],
//                     G=A@out_w2+out_b
// bx>=16:  A=context: Ftp=exp(2*(A@attn_w+attn_b)) packed^T bf16,
//                     Ht=(A@out_w1)^T bf16
// ---------------------------------------------------------------------------
__global__ __launch_bounds__(256) void ef_gemm(
    const float* __restrict__ output, const float* __restrict__ context,
    const float* __restrict__ dec_w, const float* __restrict__ attn_w,
    const float* __restrict__ out_w,
    const float* __restrict__ dec_b, const float* __restrict__ attn_b,
    const float* __restrict__ out_b,
    float* __restrict__ E2, u16* __restrict__ Ftp,
    float* __restrict__ G, u16* __restrict__ Ht) {
  int bx = blockIdx.x;
  bool isF = bx >= 16;
  const float* A  = isF ? context : output;
  const float* B1 = isF ? attn_w : dec_w;
  const float* B2 = isF ? out_w : out_w + 512 * 512;
  const float* bias1 = isF ? attn_b : dec_b;
  int m0 = (isF ? bx - 16 : bx) * 64;
  int n0 = blockIdx.y * 64;

  __shared__ u16 As[64][40];
  __shared__ u16 Bs1[64][40];
  __shared__ u16 Bs2[64][40];
  int t = threadIdx.x;
  int lane = t & 63, wid = t >> 6, wm = wid >> 1, wn = wid & 1;
  int ar = t >> 2, ac = (t & 3) * 8;
  int bn = t & 63, bk0 = (t >> 6) * 8;
  int fr = lane & 15, fh = (lane >> 4) * 8;

  const f32x4 fzero = {0.f, 0.f, 0.f, 0.f};
  f32x4 acc1[2][2], acc2[2][2];
#pragma unroll
  for (int i = 0; i < 2; ++i)
#pragma unroll
    for (int j = 0; j < 2; ++j) { acc1[i][j] = fzero; acc2[i][j] = fzero; }

  short8 av, bv1, bv2;
  auto loadA = [&](int k0) {
    const float* p = A + (size_t)(m0 + ar) * 512 + k0 + ac;
    av = cvt8(*(const f32x4*)p, *(const f32x4*)(p + 4));
  };
  auto loadB = [&](const float* B, int k0, short8& dst) {
    const float* p = B + (size_t)(k0 + bk0) * 512 + n0 + bn;
#pragma unroll
    for (int i = 0; i < 8; ++i) dst[i] = (short)f2bf(p[(size_t)i * 512]);
  };

  loadA(0); loadB(B1, 0, bv1); loadB(B2, 0, bv2);
  for (int k0 = 0; k0 < 512; k0 += 32) {
    if (k0) __syncthreads();
    *(short8*)&As[ar][ac] = av;
    *(short8*)&Bs1[bn][bk0] = bv1;
    *(short8*)&Bs2[bn][bk0] = bv2;
    __syncthreads();
    short8 a0 = *(const short8*)&As[wm * 32 + fr][fh];
    short8 a1 = *(const short8*)&As[wm * 32 + 16 + fr][fh];
    short8 p0 = *(const short8*)&Bs1[wn * 32 + fr][fh];
    short8 p1 = *(const short8*)&Bs1[wn * 32 + 16 + fr][fh];
    short8 r0 = *(const short8*)&Bs2[wn * 32 + fr][fh];
    short8 r1 = *(const short8*)&Bs2[wn * 32 + 16 + fr][fh];
    if (k0 + 32 < 512) { loadA(k0 + 32); loadB(B1, k0 + 32, bv1); loadB(B2, k0 + 32, bv2); }
    acc1[0][0] = __builtin_amdgcn_mfma_f32_16x16x32_bf16(a0, p0, acc1[0][0], 0, 0, 0);
    acc1[0][1] = __builtin_amdgcn_mfma_f32_16x16x32_bf16(a0, p1, acc1[0][1], 0, 0, 0);
    acc1[1][0] = __builtin_amdgcn_mfma_f32_16x16x32_bf16(a1, p0, acc1[1][0], 0, 0, 0);
    acc1[1][1] = __builtin_amdgcn_mfma_f32_16x16x32_bf16(a1, p1, acc1[1][1], 0, 0, 0);
    acc2[0][0] = __builtin_amdgcn_mfma_f32_16x16x32_bf16(a0, r0, acc2[0][0], 0, 0, 0);
    acc2[0][1] = __builtin_amdgcn_mfma_f32_16x16x32_bf16(a0, r1, acc2[0][1], 0, 0, 0);
    acc2[1][0] = __builtin_amdgcn_mfma_f32_16x16x32_bf16(a1, r0, acc2[1][0], 0, 0, 0);
    acc2[1][1] = __builtin_amdgcn_mfma_f32_16x16x32_bf16(a1, r1, acc2[1][1], 0, 0, 0);
  }

  // C/D layout (m89): col = lane&15, row = (lane>>4)*4 + j
#pragma unroll
  for (int qa = 0; qa < 2; ++qa) {
    int rbase = wm * 32 + qa * 16 + ((lane >> 4) << 2);
#pragma unroll
    for (int qn = 0; qn < 2; ++qn) {
      int col = n0 + wn * 32 + qn * 16 + (lane & 15);
      float b1v = bias1[col];
      int bb = m0 >> 9;
      int srow = (m0 & 511) + rbase;
      if (isF) {
        size_t fbase = ((size_t)bb * 64 + (col >> 3)) * 4096 + (size_t)(col & 7);
        short4v ho;
#pragma unroll
        for (int j = 0; j < 4; ++j) {
          float v1 = __builtin_amdgcn_exp2f((acc1[qa][qn][j] + b1v) * TANH_SCALE);
          Ftp[fbase + (size_t)(srow + j) * 8] = f2bf(v1);
          ho[j] = (short)f2bf(acc2[qa][qn][j]);
        }
        *(short4v*)&Ht[((size_t)bb * 512 + col) * 512 + srow] = ho;
      } else {
        float b2v = out_b[col];
#pragma unroll
        for (int j = 0; j < 4; ++j) {
          float v1 = __builtin_amdgcn_exp2f((acc1[qa][qn][j] + b1v) * TANH_SCALE);
          int row = m0 + rbase + j;
          E2[(((size_t)row >> 1) * 512 + col) * 2 + (row & 1)] = v1;
          G[(size_t)row * 512 + col] = acc2[qa][qn][j] + b2v;
        }
      }
    }
  }
}

// ---------------------------------------------------------------------------
// final: out = tanh(attn_bf @ Ht^T + G). 32x64 tile, grid (32,8).
// ---------------------------------------------------------------------------
__global__ __launch_bounds__(256) void final_gemm(
    const u16* __restrict__ attn_bf, const u16* __restrict__ Ht,
    const float* __restrict__ G, float* __restrict__ out) {
  int m0 = blockIdx.x * 32, n0 = blockIdx.y * 64;
  int b = m0 >> 7;   // T = 128
  const u16* Htb = Ht + (size_t)b * 512 * 512;

  __shared__ u16 As[32][40];
  __shared__ u16 Bs[64][40];
  int t = threadIdx.x;
  int lane = t & 63, wid = t >> 6, wm = wid >> 1, wn = wid & 1;
  int ar = t >> 2, ac = (t & 3) * 8;
  int bn = t & 63, bk0 = (t >> 6) * 8;
  int fr = lane & 15, fh = (lane >> 4) * 8;

  const f32x4 fzero = {0.f, 0.f, 0.f, 0.f};
  f32x4 acc[2] = {fzero, fzero};

  short8 av, bv;
  auto loadA = [&](int k0) {
    if (t < 128)
      av = *(const short8*)(attn_bf + (size_t)(m0 + ar) * 512 + k0 + ac);
  };
  auto loadB = [&](int k0) {
    bv = *(const short8*)(Htb + (size_t)(n0 + bn) * 512 + k0 + bk0);
  };

  loadA(0); loadB(0);
  for (int k0 = 0; k0 < 512; k0 += 32) {
    if (k0) __syncthreads();
    if (t < 128) *(short8*)&As[ar][ac] = av;
    *(short8*)&Bs[bn][bk0] = bv;
    __syncthreads();
    short8 a0 = *(const short8*)&As[wm * 16 + fr][fh];
    short8 b0 = *(const short8*)&Bs[wn * 32 + fr][fh];
    short8 b1 = *(const short8*)&Bs[wn * 32 + 16 + fr][fh];
    if (k0 + 32 < 512) { loadA(k0 + 32); loadB(k0 + 32); }
    acc[0] = __builtin_amdgcn_mfma_f32_16x16x32_bf16(a0, b0, acc[0], 0, 0, 0);
    acc[1] = __builtin_amdgcn_mfma_f32_16x16x32_bf16(a0, b1, acc[1], 0, 0, 0);
  }

  int row0 = m0 + wm * 16 + ((lane >> 4) << 2);
#pragma unroll
  for (int qn = 0; qn < 2; ++qn) {
    int col = n0 + wn * 32 + qn * 16 + (lane & 15);
#pragma unroll
    for (int j = 0; j < 4; ++j) {
      float v = acc[qn][j] + G[(size_t)(row0 + j) * 512 + col];
      float e = __builtin_amdgcn_exp2f(v * TANH_SCALE);
      v = fmaf(-2.0f, __builtin_amdgcn_rcpf(e + 1.0f), 1.0f);
      out[(size_t)(row0 + j) * 512 + col] = v;
    }
  }
}

// ---------------------------------------------------------------------------
// Fused logits+softmax, packed-f32 (v_pk_*) over row pairs (R17 exact).
// grid = B*T/4 = 256 (XCD-swizzled), block = 1024 (16 waves).
// Wave (gh, sc): rows bt0..bt0+3 as 2 pairs, g in [gh*32,+32), s-chunk sc.
// E2[(t>>1)*512+d][2]: one f32x4 load = 2 d x 2 rows, no shuffles.
// l = -2*sum(q*r) directly (softmax shift-invariant: qsum+qb dropped).
// ---------------------------------------------------------------------------
__global__ __launch_bounds__(1024) void logits_softmax_kernel(
    const float* __restrict__ E2, const u16* __restrict__ Ftp,
    const float* __restrict__ qw,
    float* __restrict__ attn, u16* __restrict__ attn_bf) {
  int bid = blockIdx.x;
  int logical = ((bid & 7) << 5) | (bid >> 3);  // batch = bid&7 per XCD
  int bt0 = logical * 4;
  int b = logical >> 5;
  int tid = threadIdx.x;
  int lane = tid & 63;
  int wv = __builtin_amdgcn_readfirstlane(tid >> 6);
  int gh = wv >> 3;
  int sc = wv & 7;
  int s = sc * 64 + lane;

  const u32x4* Fp = (const u32x4*)(Ftp + (size_t)b * 262144 + (size_t)s * 8);
  const float* E2p0 = E2 + ((size_t)(bt0 >> 1)) * 1024;   // pair0: rows bt0,bt0+1
  const float* E2p1 = E2p0 + 1024;                        // pair1

  const f32x2 one2 = {1.f, 1.f};
  f32x2 aP0A = {0.f, 0.f}, aP0B = {0.f, 0.f};
  f32x2 aP1A = {0.f, 0.f}, aP1B = {0.f, 0.f};

  auto quadpk = [&](f32x2 e0, f32x2 e1, f32x2 e2, f32x2 e3,
                    f32x2 ff0, f32x2 ff1, f32x2 ff2, f32x2 ff3,
                    float q0, float q1, float q2, float q3, f32x2& acc) {
    f32x2 x0 = e0 * ff0 + one2, x1 = e1 * ff1 + one2;
    f32x2 x2 = e2 * ff2 + one2, x3 = e3 * ff3 + one2;
    f32x2 dA = x0 * x1, dB = x2 * x3;
    f32x2 nA = q0 * x1 + q1 * x0;
    f32x2 nB = q2 * x3 + q3 * x2;
    f32x2 N = nA * dB + nB * dA;
    f32x2 D = dA * dB;
    f32x2 r;
    r.x = __builtin_amdgcn_rcpf(D.x);
    r.y = __builtin_amdgcn_rcpf(D.y);
    acc += N * r;
  };

  int gbase = gh * 32;
#pragma unroll 2
  for (int gg = 0; gg < 32; ++gg) {
    int g = gbase + gg;
    u32x4 w = Fp[(size_t)g * 512];   // per-g stride = 8192 B = 512 u32x4
    f32x2 ff0 = splat2(bflo2f(w[0])), ff1 = splat2(bfhi2f(w[0]));
    f32x2 ff2 = splat2(bflo2f(w[1])), ff3 = splat2(bfhi2f(w[1]));
    f32x2 ff4 = splat2(bflo2f(w[2])), ff5 = splat2(bfhi2f(w[2]));
    f32x2 ff6 = splat2(bflo2f(w[3])), ff7 = splat2(bfhi2f(w[3]));
    f32x4 q0v = *(const f32x4*)(qw + g * 8);
    f32x4 q1v = *(const f32x4*)(qw + g * 8 + 4);
    f32x4 ea0 = *(const f32x4*)(E2p0 + g * 16);
    f32x4 eb0 = *(const f32x4*)(E2p0 + g * 16 + 4);
    f32x4 ec0 = *(const f32x4*)(E2p0 + g * 16 + 8);
    f32x4 ed0 = *(const f32x4*)(E2p0 + g * 16 + 12);
    f32x4 ea1 = *(const f32x4*)(E2p1 + g * 16);
    f32x4 eb1 = *(const f32x4*)(E2p1 + g * 16 + 4);
    f32x4 ec1 = *(const f32x4*)(E2p1 + g * 16 + 8);
    f32x4 ed1 = *(const f32x4*)(E2p1 + g * 16 + 12);
    quadpk(vlo(ea0), vhi(ea0), vlo(eb0), vhi(eb0),
           ff0, ff1, ff2, ff3, q0v[0], q0v[1], q0v[2], q0v[3], aP0A);
    quadpk(vlo(ec0), vhi(ec0), vlo(ed0), vhi(ed0),
           ff4, ff5, ff6, ff7, q1v[0], q1v[1], q1v[2], q1v[3], aP0B);
    quadpk(vlo(ea1), vhi(ea1), vlo(eb1), vhi(eb1),
           ff0, ff1, ff2, ff3, q0v[0], q0v[1], q0v[2], q0v[3], aP1A);
    quadpk(vlo(ec1), vhi(ec1), vlo(ed1), vhi(ed1),
           ff4, ff5, ff6, ff7, q1v[0], q1v[1], q1v[2], q1v[3], aP1B);
  }

  __shared__ float part[2][4][512];   // [gh][row][s]  16 KB
  part[gh][0][s] = aP0A.x + aP0B.x;
  part[gh][1][s] = aP0A.y + aP0B.y;
  part[gh][2][s] = aP1A.x + aP1B.x;
  part[gh][3][s] = aP1A.y + aP1B.y;
  __syncthreads();

  // combine + softmax: row r = tid>>8 (0..3), cols ss and ss+256.
  int r = tid >> 8;
  int ss = tid & 255;
  int wir = (tid >> 6) & 3;
  float l0 = -2.f * (part[0][r][ss] + part[1][r][ss]);
  float l1 = -2.f * (part[0][r][ss + 256] + part[1][r][ss + 256]);

  __shared__ float rmax[4][4], rsum[4][4];
  float m = fmaxf(l0, l1);
#pragma unroll
  for (int off = 32; off > 0; off >>= 1) m = fmaxf(m, __shfl_xor(m, off, 64));
  if (lane == 0) rmax[r][wir] = m;
  __syncthreads();
  float M = fmaxf(fmaxf(rmax[r][0], rmax[r][1]), fmaxf(rmax[r][2], rmax[r][3]));
  float ex0 = __builtin_amdgcn_exp2f((l0 - M) * LOG2E);
  float ex1 = __builtin_amdgcn_exp2f((l1 - M) * LOG2E);
  float sv = ex0 + ex1;
#pragma unroll
  for (int off = 32; off > 0; off >>= 1) sv += __shfl_xor(sv, off, 64);
  if (lane == 0) rsum[r][wir] = sv;
  __syncthreads();
  float S = (rsum[r][0] + rsum[r][1]) + (rsum[r][2] + rsum[r][3]);
  float inv = __builtin_amdgcn_rcpf(S);
  float o0 = ex0 * inv, o1 = ex1 * inv;
  size_t i0 = (size_t)(bt0 + r) * 512 + ss;
  attn[i0] = o0;
  attn[i0 + 256] = o1;
  attn_bf[i0] = f2bf(o0);
  attn_bf[i0 + 256] = f2bf(o1);
}

extern "C" void kernel_launch(void* const* d_in, const int* in_sizes, int n_in,
                              void* d_out, int out_size, void* d_ws, size_t ws_size,
                              hipStream_t stream) {
  const float* output  = (const float*)d_in[0];  // [B,T,D]
  const float* context = (const float*)d_in[1];  // [B,S,C]
  const float* dec_w   = (const float*)d_in[2];  // [D,D]
  const float* dec_b   = (const float*)d_in[3];
  const float* attn_w  = (const float*)d_in[4];  // [C,D]
  const float* attn_b  = (const float*)d_in[5];
  const float* qw      = (const float*)d_in[6];  // [D,1]
  const float* qb      = (const float*)d_in[7];  // [1]  (unused: softmax-invariant)
  const float* out_w   = (const float*)d_in[8];  // [1024,512]
  const float* out_b   = (const float*)d_in[9];
  (void)qb;

  float* out_p  = (float*)d_out;                     // [B,T,D]
  float* attn_p = out_p + (size_t)BB * TT_DIM * DD;  // [B,T,S]

  char* p = (char*)d_ws;
  float* E2   = (float*)p; p += (size_t)BB * TT_DIM * DD * 4;  // 2MB interleaved
  u16* Ftp    = (u16*)p;   p += (size_t)BB * SS * DD * 2;      // 4MB packed^T bf16
  float* G    = (float*)p; p += (size_t)BB * TT_DIM * DD * 4;  // 2MB
  u16* Ht     = (u16*)p;   p += (size_t)BB * SS * DD * 2;      // 4MB bf16 ^T
  u16* attnbf = (u16*)p;   p += (size_t)BB * TT_DIM * SS * 2;  // 1MB

  ef_gemm<<<dim3(80, 8), 256, 0, stream>>>(output, context, dec_w, attn_w,
                                           out_w, dec_b, attn_b, out_b,
                                           E2, Ftp, G, Ht);
  logits_softmax_kernel<<<dim3(BB * TT_DIM / 4), 1024, 0, stream>>>(
      E2, Ftp, qw, attn_p, attnbf);
  final_gemm<<<dim3(32, 8), 256, 0, stream>>>(attnbf, Ht, G, out_p);
}